// Round 1
// baseline (9578.140 us; speedup 1.0000x reference)
//
#include <hip/hip_runtime.h>
#include <math.h>

#define DMODEL 1024
#define SEQ 2048
#define BATCH 4
#define SCALE_INV (1.0f/32.0f)   // 1/sqrt(1024)

// ---------------------------------------------------------------------------
// QKV projection: out[m,n] = sum_k x[m,k] * W[k,n] + b[n]
// M = B*S = 8192, N = K = 1024.  blockIdx.z selects {Q,K,V}.
// 32x32 tile, 1024 threads, LDS-staged, fp32.
// ---------------------------------------------------------------------------
__global__ __launch_bounds__(1024) void qkv_gemm(
    const float* __restrict__ x,
    const float* __restrict__ Wq, const float* __restrict__ bq,
    const float* __restrict__ Wk, const float* __restrict__ bk,
    const float* __restrict__ Wv, const float* __restrict__ bv,
    float* __restrict__ q, float* __restrict__ k, float* __restrict__ v)
{
    const float* W; const float* bias; float* out;
    const int z = blockIdx.z;
    if (z == 0)      { W = Wq; bias = bq; out = q; }
    else if (z == 1) { W = Wk; bias = bk; out = k; }
    else             { W = Wv; bias = bv; out = v; }

    __shared__ float As[32][33];
    __shared__ float Bs[32][33];
    const int tx = threadIdx.x, ty = threadIdx.y;
    const int row = blockIdx.y * 32 + ty;   // m  (always in-bounds: 8192 % 32 == 0)
    const int col = blockIdx.x * 32 + tx;   // n  (1024 % 32 == 0)

    float acc = 0.f;
    for (int k0 = 0; k0 < DMODEL; k0 += 32) {
        As[ty][tx] = x[(size_t)row * DMODEL + k0 + tx];
        Bs[ty][tx] = W[(size_t)(k0 + ty) * DMODEL + col];
        __syncthreads();
        #pragma unroll
        for (int kk = 0; kk < 32; ++kk)
            acc += As[ty][kk] * Bs[kk][tx];
        __syncthreads();
    }
    out[(size_t)row * DMODEL + col] = acc + bias[col];
}

// ---------------------------------------------------------------------------
// Causal attention, one block (256 threads) per (query row s, batch b).
// Scores for all t <= s fit in LDS (8 KB). Softmax in-block, then coalesced
// PV accumulation (thread j owns d = j, j+256, j+512, j+768).
// ---------------------------------------------------------------------------
__global__ __launch_bounds__(256) void attn_kernel(
    const float* __restrict__ q,
    const float* __restrict__ k,
    const float* __restrict__ v,
    float* __restrict__ out)
{
    const int s = blockIdx.x;
    const int b = blockIdx.y;
    const int tid = threadIdx.x;

    __shared__ float qs[DMODEL];   // 4 KB
    __shared__ float sc[SEQ];      // 8 KB
    __shared__ float red[256];     // 1 KB

    const float* qrow = q + ((size_t)b * SEQ + s) * DMODEL;
    for (int d = tid; d < DMODEL; d += 256) qs[d] = qrow[d];
    __syncthreads();

    const float* kb = k + (size_t)b * SEQ * DMODEL;
    const int nt = s + 1;            // causal: t in [0, s]

    // --- scores ---
    float lmax = -INFINITY;
    for (int t = tid; t < nt; t += 256) {
        const float* krow = kb + (size_t)t * DMODEL;
        float acc = 0.f;
        for (int d = 0; d < DMODEL; d += 4) {
            const float4 kv = *(const float4*)(krow + d);
            acc += qs[d] * kv.x + qs[d+1] * kv.y + qs[d+2] * kv.z + qs[d+3] * kv.w;
        }
        acc *= SCALE_INV;
        sc[t] = acc;
        lmax = fmaxf(lmax, acc);
    }
    red[tid] = lmax;
    __syncthreads();
    for (int off = 128; off > 0; off >>= 1) {
        if (tid < off) red[tid] = fmaxf(red[tid], red[tid + off]);
        __syncthreads();
    }
    const float mx = red[0];
    __syncthreads();

    // --- exp + sum ---
    float lsum = 0.f;
    for (int t = tid; t < nt; t += 256) {
        const float e = expf(sc[t] - mx);
        sc[t] = e;
        lsum += e;
    }
    red[tid] = lsum;
    __syncthreads();
    for (int off = 128; off > 0; off >>= 1) {
        if (tid < off) red[tid] += red[tid + off];
        __syncthreads();
    }
    const float inv = 1.0f / red[0];
    __syncthreads();

    // --- PV ---
    const float* vb = v + (size_t)b * SEQ * DMODEL;
    float a0 = 0.f, a1 = 0.f, a2 = 0.f, a3 = 0.f;
    for (int t = 0; t < nt; ++t) {
        const float p = sc[t];
        const float* vrow = vb + (size_t)t * DMODEL;
        a0 += p * vrow[tid        ];
        a1 += p * vrow[tid + 256  ];
        a2 += p * vrow[tid + 512  ];
        a3 += p * vrow[tid + 768  ];
    }
    float* orow = out + ((size_t)b * SEQ + s) * DMODEL;
    orow[tid        ] = a0 * inv;
    orow[tid + 256  ] = a1 * inv;
    orow[tid + 512  ] = a2 * inv;
    orow[tid + 768  ] = a3 * inv;
}

// ---------------------------------------------------------------------------
extern "C" void kernel_launch(void* const* d_in, const int* in_sizes, int n_in,
                              void* d_out, int out_size, void* d_ws, size_t ws_size,
                              hipStream_t stream)
{
    const float* x  = (const float*)d_in[0];
    // d_in[1] = mask (int32 tril) — causal structure is hardcoded
    const float* Wq = (const float*)d_in[2];
    const float* bq = (const float*)d_in[3];
    const float* Wk = (const float*)d_in[4];
    const float* bk = (const float*)d_in[5];
    const float* Wv = (const float*)d_in[6];
    const float* bv = (const float*)d_in[7];
    float* out = (float*)d_out;

    const size_t elems = (size_t)BATCH * SEQ * DMODEL;   // 8.4M elements, 32 MB
    float* q = (float*)d_ws;
    float* k = q + elems;
    float* v = k + elems;   // total ws use: 96 MB

    dim3 gemm_grid(DMODEL / 32, (BATCH * SEQ) / 32, 3);
    dim3 gemm_block(32, 32);
    hipLaunchKernelGGL(qkv_gemm, gemm_grid, gemm_block, 0, stream,
                       x, Wq, bq, Wk, bk, Wv, bv, q, k, v);

    dim3 attn_grid(SEQ, BATCH);
    hipLaunchKernelGGL(attn_kernel, attn_grid, dim3(256), 0, stream,
                       q, k, v, out);
}

// Round 2
// 221.155 us; speedup vs baseline: 43.3096x; 43.3096x over previous
//
#include <hip/hip_runtime.h>
#include <math.h>

#define DMODEL 1024
#define SEQ 2048
#define BATCH 4
#define SCALE_INV (1.0f/32.0f)   // 1/sqrt(1024)

typedef unsigned short ushort_t;
typedef __attribute__((ext_vector_type(8))) short bf16x8;   // 8 bf16 in 4 VGPRs
typedef __attribute__((ext_vector_type(4))) float f32x4;

// fp32 -> bf16, round-to-nearest-even (bit manipulation; header-type independent)
__device__ __forceinline__ ushort_t f2bf(float f) {
    unsigned int u = __float_as_uint(f);
    unsigned int rounding = 0x7FFFu + ((u >> 16) & 1u);
    return (ushort_t)((u + rounding) >> 16);
}

#define GLOAD16(SRC, DST) \
    __builtin_amdgcn_global_load_lds( \
        (const __attribute__((address_space(1))) void*)(SRC), \
        (__attribute__((address_space(3))) void*)(DST), 16, 0, 0)

// ---------------------------------------------------------------------------
// Shared MFMA GEMM core: C(128x128) += A(128xK) * Bt(128xK)^T
// A row-major MxK (lda), Bt row-major NxK (ldb) -- i.e. B^T layout, both
// K-contiguous. 256 threads = 4 waves in 2x2; each wave owns 64x64 = 4x4
// fragments of 16x16x32 bf16 MFMA. BK=32. m97-style 2-barrier loop with
// global_load_lds width-16 staging.
// Fragment layouts (HW-verified m89/m97):
//   A/B: 8 contiguous K elems at row/col = lane&15, k0 = (lane>>4)*8
//   C/D: col = lane&15, row = (lane>>4)*4 + reg
// ---------------------------------------------------------------------------
__device__ __forceinline__ void gemm_core_128(
    const ushort_t* __restrict__ A, int lda,
    const ushort_t* __restrict__ Bt, int ldb,
    int arow0, int brow0, int ksteps,
    ushort_t* As, ushort_t* Bs,
    f32x4 acc[4][4])
{
    const int tid = threadIdx.x;
    const int l   = tid & 63;
    const int w   = tid >> 6;      // wave 0..3
    const int wr  = w >> 1;        // wave row (0..1)
    const int wc  = w & 1;         // wave col (0..1)

    for (int s = 0; s < ksteps; ++s) {
        const int k0 = s * 32;
        // --- stage A tile (128x32 bf16 = 8 KB): 2 issues x 4 waves x 64 lanes x 16B
        #pragma unroll
        for (int i = 0; i < 2; ++i) {
            const int off = i * 4096 + w * 1024 + l * 16;   // byte offset in As
            const int row = off >> 6;                        // 64 B per row
            const int ke  = (off & 63) >> 1;                 // bf16 elem in row
            GLOAD16(A + (size_t)(arow0 + row) * lda + k0 + ke,
                    (char*)As + i * 4096 + w * 1024);
        }
        // --- stage B tile (128x32)
        #pragma unroll
        for (int i = 0; i < 2; ++i) {
            const int off = i * 4096 + w * 1024 + l * 16;
            const int row = off >> 6;
            const int ke  = (off & 63) >> 1;
            GLOAD16(Bt + (size_t)(brow0 + row) * ldb + k0 + ke,
                    (char*)Bs + i * 4096 + w * 1024);
        }
        __syncthreads();   // drains vmcnt(0) then barrier

        bf16x8 a[4], b[4];
        #pragma unroll
        for (int m = 0; m < 4; ++m)
            a[m] = *(const bf16x8*)(As + (wr * 64 + m * 16 + (l & 15)) * 32 + (l >> 4) * 8);
        #pragma unroll
        for (int n = 0; n < 4; ++n)
            b[n] = *(const bf16x8*)(Bs + (wc * 64 + n * 16 + (l & 15)) * 32 + (l >> 4) * 8);
        #pragma unroll
        for (int m = 0; m < 4; ++m)
            #pragma unroll
            for (int n = 0; n < 4; ++n)
                acc[m][n] = __builtin_amdgcn_mfma_f32_16x16x32_bf16(a[m], b[n], acc[m][n], 0, 0, 0);
        __syncthreads();   // protect LDS before next staging
    }
}

// ---------------------------------------------------------------------------
// QKV projection: out = x @ W + b  (W^T pre-transposed to N x K bf16).
// blockIdx.z selects Q (scaled by 1/sqrt(D)) / K / V. Output bf16.
// ---------------------------------------------------------------------------
__global__ __launch_bounds__(256) void qkv_gemm_mfma(
    const ushort_t* __restrict__ x,
    const ushort_t* __restrict__ wtq, const ushort_t* __restrict__ wtk, const ushort_t* __restrict__ wtv,
    const float* __restrict__ bq, const float* __restrict__ bk, const float* __restrict__ bv,
    ushort_t* __restrict__ q, ushort_t* __restrict__ k, ushort_t* __restrict__ v)
{
    __shared__ __align__(16) ushort_t As[128 * 32];
    __shared__ __align__(16) ushort_t Bs[128 * 32];

    const ushort_t* Bt; const float* bias; ushort_t* out; float scale;
    const int z = blockIdx.z;
    if (z == 0)      { Bt = wtq; bias = bq; out = q; scale = SCALE_INV; }
    else if (z == 1) { Bt = wtk; bias = bk; out = k; scale = 1.0f; }
    else             { Bt = wtv; bias = bv; out = v; scale = 1.0f; }

    const int arow0 = blockIdx.y * 128;
    const int brow0 = blockIdx.x * 128;

    f32x4 acc[4][4];
    #pragma unroll
    for (int m = 0; m < 4; ++m)
        #pragma unroll
        for (int n = 0; n < 4; ++n)
            acc[m][n] = (f32x4)(0.f);

    gemm_core_128(x, DMODEL, Bt, DMODEL, arow0, brow0, DMODEL / 32, As, Bs, acc);

    const int l  = threadIdx.x & 63;
    const int w  = threadIdx.x >> 6;
    const int wr = w >> 1, wc = w & 1;
    #pragma unroll
    for (int n = 0; n < 4; ++n) {
        const int gcol = brow0 + wc * 64 + n * 16 + (l & 15);
        const float bb = bias[gcol];
        #pragma unroll
        for (int m = 0; m < 4; ++m) {
            #pragma unroll
            for (int j = 0; j < 4; ++j) {
                const int grow = arow0 + wr * 64 + m * 16 + (l >> 4) * 4 + j;
                out[(size_t)grow * DMODEL + gcol] = f2bf((acc[m][n][j] + bb) * scale);
            }
        }
    }
}

// ---------------------------------------------------------------------------
// scores = Q K^T  (scale already folded into Q). Triangular block skip.
// Output fp32, ldc = SEQ.
// ---------------------------------------------------------------------------
__global__ __launch_bounds__(256) void qkt_gemm_mfma(
    const ushort_t* __restrict__ q, const ushort_t* __restrict__ k,
    float* __restrict__ scores)
{
    const int tt = blockIdx.x;   // t tile
    const int st = blockIdx.y;   // s tile
    const int b  = blockIdx.z;
    if (tt > st) return;         // fully masked block

    __shared__ __align__(16) ushort_t As[128 * 32];
    __shared__ __align__(16) ushort_t Bs[128 * 32];

    const ushort_t* A  = q + (size_t)b * SEQ * DMODEL;
    const ushort_t* Bt = k + (size_t)b * SEQ * DMODEL;
    float* out = scores + (size_t)b * SEQ * SEQ;

    f32x4 acc[4][4];
    #pragma unroll
    for (int m = 0; m < 4; ++m)
        #pragma unroll
        for (int n = 0; n < 4; ++n)
            acc[m][n] = (f32x4)(0.f);

    gemm_core_128(A, DMODEL, Bt, DMODEL, st * 128, tt * 128, DMODEL / 32, As, Bs, acc);

    const int l  = threadIdx.x & 63;
    const int w  = threadIdx.x >> 6;
    const int wr = w >> 1, wc = w & 1;
    #pragma unroll
    for (int m = 0; m < 4; ++m) {
        #pragma unroll
        for (int n = 0; n < 4; ++n) {
            const int gcol = tt * 128 + wc * 64 + n * 16 + (l & 15);
            #pragma unroll
            for (int j = 0; j < 4; ++j) {
                const int grow = st * 128 + wr * 64 + m * 16 + (l >> 4) * 4 + j;
                out[(size_t)grow * SEQ + gcol] = acc[m][n][j];
            }
        }
    }
}

// ---------------------------------------------------------------------------
// Row softmax over causal prefix. Writes P (bf16) IN PLACE over the score
// row (P row = first SEQ ushorts of the fp32 row; ld_ushort = 2*SEQ).
// Zero-fills t in (s, rounded-up tile boundary) so PV can read full tiles.
// ---------------------------------------------------------------------------
__global__ __launch_bounds__(256) void softmax_rows(float* __restrict__ scores)
{
    const int s = blockIdx.x;
    const int b = blockIdx.y;
    const int tid = threadIdx.x;

    float* row = scores + ((size_t)b * SEQ + s) * SEQ;
    ushort_t* prow = (ushort_t*)row;
    const int nt = s + 1;

    __shared__ float e_sh[SEQ];    // 8 KB
    __shared__ float red[256];

    float lmax = -INFINITY;
    for (int t = tid; t < nt; t += 256) {
        const float xv = row[t];
        e_sh[t] = xv;
        lmax = fmaxf(lmax, xv);
    }
    red[tid] = lmax;
    __syncthreads();
    for (int off = 128; off > 0; off >>= 1) {
        if (tid < off) red[tid] = fmaxf(red[tid], red[tid + off]);
        __syncthreads();
    }
    const float mx = red[0];
    __syncthreads();

    float lsum = 0.f;
    for (int t = tid; t < nt; t += 256) {
        const float e = expf(e_sh[t] - mx);
        e_sh[t] = e;
        lsum += e;
    }
    red[tid] = lsum;
    __syncthreads();
    for (int off = 128; off > 0; off >>= 1) {
        if (tid < off) red[tid] += red[tid + off];
        __syncthreads();
    }
    const float inv = 1.0f / red[0];
    __syncthreads();   // all reads of `row` and e_sh writes done before overwrite

    const int tmax = ((s >> 7) + 1) << 7;   // round_up(s+1, 128)
    for (int t = tid; t < tmax; t += 256)
        prow[t] = (t < nt) ? f2bf(e_sh[t] * inv) : (ushort_t)0;
}

// ---------------------------------------------------------------------------
// out = P @ V. P bf16 lives inside the fp32 score buffer (ld = 2*SEQ ushorts).
// V^T (D x S) bf16 so B fragments are K(=t)-contiguous. K-loop stops at the
// causal tile boundary. Output fp32 directly to d_out.
// ---------------------------------------------------------------------------
__global__ __launch_bounds__(256) void pv_gemm_mfma(
    const float* __restrict__ scoresP, const ushort_t* __restrict__ vt,
    float* __restrict__ outp)
{
    const int dt = blockIdx.x;   // d tile (N)
    const int st = blockIdx.y;   // s tile (M)
    const int b  = blockIdx.z;

    __shared__ __align__(16) ushort_t As[128 * 32];
    __shared__ __align__(16) ushort_t Bs[128 * 32];

    const ushort_t* A  = (const ushort_t*)(scoresP + (size_t)b * SEQ * SEQ);  // lda = 2*SEQ
    const ushort_t* Bt = vt + (size_t)b * DMODEL * SEQ;                        // ldb = SEQ
    float* out = outp + (size_t)b * SEQ * DMODEL;

    f32x4 acc[4][4];
    #pragma unroll
    for (int m = 0; m < 4; ++m)
        #pragma unroll
        for (int n = 0; n < 4; ++n)
            acc[m][n] = (f32x4)(0.f);

    const int ksteps = (st + 1) * 4;   // (s0+128)/32 K-steps of 32
    gemm_core_128(A, 2 * SEQ, Bt, SEQ, st * 128, dt * 128, ksteps, As, Bs, acc);

    const int l  = threadIdx.x & 63;
    const int w  = threadIdx.x >> 6;
    const int wr = w >> 1, wc = w & 1;
    #pragma unroll
    for (int m = 0; m < 4; ++m) {
        #pragma unroll
        for (int n = 0; n < 4; ++n) {
            const int gcol = dt * 128 + wc * 64 + n * 16 + (l & 15);
            #pragma unroll
            for (int j = 0; j < 4; ++j) {
                const int grow = st * 128 + wr * 64 + m * 16 + (l >> 4) * 4 + j;
                out[(size_t)grow * DMODEL + gcol] = acc[m][n][j];
            }
        }
    }
}

// ---------------------------------------------------------------------------
// Helpers: fp32 -> bf16 conversions / transposes
// ---------------------------------------------------------------------------
__global__ __launch_bounds__(256) void convert_bf16(
    const float* __restrict__ in, ushort_t* __restrict__ out, int n4)
{
    const int i = (blockIdx.x * 256 + threadIdx.x);
    if (i < n4) {
        const float4 f = *(const float4*)(in + (size_t)i * 4);
        ushort4 o;
        o.x = f2bf(f.x); o.y = f2bf(f.y); o.z = f2bf(f.z); o.w = f2bf(f.w);
        *(ushort4*)(out + (size_t)i * 4) = o;
    }
}

// W (K x N fp32) -> W^T (N x K bf16); z selects Wq/Wk/Wv
__global__ __launch_bounds__(256) void transpose_w(
    const float* __restrict__ Wq, const float* __restrict__ Wk, const float* __restrict__ Wv,
    ushort_t* __restrict__ wtq, ushort_t* __restrict__ wtk, ushort_t* __restrict__ wtv)
{
    const float* W; ushort_t* wt;
    const int z = blockIdx.z;
    if (z == 0)      { W = Wq; wt = wtq; }
    else if (z == 1) { W = Wk; wt = wtk; }
    else             { W = Wv; wt = wtv; }

    __shared__ float tile[32][33];
    const int k0 = blockIdx.x * 32, n0 = blockIdx.y * 32;
    const int x = threadIdx.x, y = threadIdx.y;
    #pragma unroll
    for (int i = 0; i < 4; ++i)
        tile[y + i * 8][x] = W[(size_t)(k0 + y + i * 8) * DMODEL + n0 + x];
    __syncthreads();
    #pragma unroll
    for (int i = 0; i < 4; ++i)
        wt[(size_t)(n0 + y + i * 8) * DMODEL + k0 + x] = f2bf(tile[x][y + i * 8]);
}

// V (B,S,D bf16) -> V^T (B,D,S bf16)
__global__ __launch_bounds__(256) void transpose_v(
    const ushort_t* __restrict__ v, ushort_t* __restrict__ vt)
{
    __shared__ ushort_t tile[32][33];
    const int b = blockIdx.z;
    const int t0 = blockIdx.x * 32, d0 = blockIdx.y * 32;
    const ushort_t* src = v + (size_t)b * SEQ * DMODEL;
    ushort_t* dst = vt + (size_t)b * DMODEL * SEQ;
    const int x = threadIdx.x, y = threadIdx.y;
    #pragma unroll
    for (int i = 0; i < 4; ++i)
        tile[y + i * 8][x] = src[(size_t)(t0 + y + i * 8) * DMODEL + d0 + x];
    __syncthreads();
    #pragma unroll
    for (int i = 0; i < 4; ++i)
        dst[(size_t)(d0 + y + i * 8) * SEQ + t0 + x] = tile[x][y + i * 8];
}

// ===========================================================================
// Fallback fp32 path (round-1 kernels) in case ws_size < MFMA needs
// ===========================================================================
__global__ __launch_bounds__(1024) void qkv_gemm_f32(
    const float* __restrict__ x,
    const float* __restrict__ Wq, const float* __restrict__ bq,
    const float* __restrict__ Wk, const float* __restrict__ bk,
    const float* __restrict__ Wv, const float* __restrict__ bv,
    float* __restrict__ q, float* __restrict__ k, float* __restrict__ v)
{
    const float* W; const float* bias; float* out;
    const int z = blockIdx.z;
    if (z == 0)      { W = Wq; bias = bq; out = q; }
    else if (z == 1) { W = Wk; bias = bk; out = k; }
    else             { W = Wv; bias = bv; out = v; }

    __shared__ float As[32][33];
    __shared__ float Bs[32][33];
    const int tx = threadIdx.x, ty = threadIdx.y;
    const int row = blockIdx.y * 32 + ty;
    const int col = blockIdx.x * 32 + tx;

    float acc = 0.f;
    for (int k0 = 0; k0 < DMODEL; k0 += 32) {
        As[ty][tx] = x[(size_t)row * DMODEL + k0 + tx];
        Bs[ty][tx] = W[(size_t)(k0 + ty) * DMODEL + col];
        __syncthreads();
        #pragma unroll
        for (int kk = 0; kk < 32; ++kk)
            acc += As[ty][kk] * Bs[kk][tx];
        __syncthreads();
    }
    out[(size_t)row * DMODEL + col] = acc + bias[col];
}

__global__ __launch_bounds__(256) void attn_f32(
    const float* __restrict__ q, const float* __restrict__ k,
    const float* __restrict__ v, float* __restrict__ out)
{
    const int s = blockIdx.x, b = blockIdx.y, tid = threadIdx.x;
    __shared__ float qs[DMODEL];
    __shared__ float sc[SEQ];
    __shared__ float red[256];
    const float* qrow = q + ((size_t)b * SEQ + s) * DMODEL;
    for (int d = tid; d < DMODEL; d += 256) qs[d] = qrow[d];
    __syncthreads();
    const float* kb = k + (size_t)b * SEQ * DMODEL;
    const int nt = s + 1;
    float lmax = -INFINITY;
    for (int t = tid; t < nt; t += 256) {
        const float* krow = kb + (size_t)t * DMODEL;
        float acc = 0.f;
        for (int d = 0; d < DMODEL; d += 4) {
            const float4 kv = *(const float4*)(krow + d);
            acc += qs[d] * kv.x + qs[d+1] * kv.y + qs[d+2] * kv.z + qs[d+3] * kv.w;
        }
        acc *= SCALE_INV; sc[t] = acc; lmax = fmaxf(lmax, acc);
    }
    red[tid] = lmax; __syncthreads();
    for (int off = 128; off > 0; off >>= 1) { if (tid < off) red[tid] = fmaxf(red[tid], red[tid+off]); __syncthreads(); }
    const float mx = red[0]; __syncthreads();
    float lsum = 0.f;
    for (int t = tid; t < nt; t += 256) { const float e = expf(sc[t]-mx); sc[t]=e; lsum+=e; }
    red[tid] = lsum; __syncthreads();
    for (int off = 128; off > 0; off >>= 1) { if (tid < off) red[tid] += red[tid+off]; __syncthreads(); }
    const float inv = 1.0f / red[0]; __syncthreads();
    const float* vb = v + (size_t)b * SEQ * DMODEL;
    float a0=0,a1=0,a2=0,a3=0;
    for (int t = 0; t < nt; ++t) {
        const float p = sc[t];
        const float* vrow = vb + (size_t)t * DMODEL;
        a0 += p*vrow[tid]; a1 += p*vrow[tid+256]; a2 += p*vrow[tid+512]; a3 += p*vrow[tid+768];
    }
    float* orow = out + ((size_t)b * SEQ + s) * DMODEL;
    orow[tid]=a0*inv; orow[tid+256]=a1*inv; orow[tid+512]=a2*inv; orow[tid+768]=a3*inv;
}

// ---------------------------------------------------------------------------
extern "C" void kernel_launch(void* const* d_in, const int* in_sizes, int n_in,
                              void* d_out, int out_size, void* d_ws, size_t ws_size,
                              hipStream_t stream)
{
    const float* x  = (const float*)d_in[0];
    // d_in[1] = mask (int32 tril) — causal structure hardcoded
    const float* Wq = (const float*)d_in[2];
    const float* bq = (const float*)d_in[3];
    const float* Wk = (const float*)d_in[4];
    const float* bk = (const float*)d_in[5];
    const float* Wv = (const float*)d_in[6];
    const float* bv = (const float*)d_in[7];
    float* out = (float*)d_out;

    // ---- MFMA path workspace layout (bytes) ----
    const size_t SZ_XBF   = (size_t)BATCH * SEQ * DMODEL * 2;      // 16 MB
    const size_t SZ_WT    = (size_t)DMODEL * DMODEL * 2;           // 2 MB each
    const size_t SZ_QKV   = (size_t)BATCH * SEQ * DMODEL * 2;      // 16 MB each
    const size_t SZ_VT    = (size_t)BATCH * DMODEL * SEQ * 2;      // 16 MB
    const size_t SZ_SC    = (size_t)BATCH * SEQ * SEQ * 4;         // 67 MB
    const size_t NEED = SZ_XBF + 3 * SZ_WT + 3 * SZ_QKV + SZ_VT + SZ_SC;  // ~150 MB

    if (ws_size >= NEED) {
        char* p = (char*)d_ws;
        ushort_t* x_bf = (ushort_t*)p;              p += SZ_XBF;
        ushort_t* wtq  = (ushort_t*)p;              p += SZ_WT;
        ushort_t* wtk  = (ushort_t*)p;              p += SZ_WT;
        ushort_t* wtv  = (ushort_t*)p;              p += SZ_WT;
        ushort_t* q_bf = (ushort_t*)p;              p += SZ_QKV;
        ushort_t* k_bf = (ushort_t*)p;              p += SZ_QKV;
        ushort_t* v_bf = (ushort_t*)p;              p += SZ_QKV;
        ushort_t* vt   = (ushort_t*)p;              p += SZ_VT;
        float*    sc   = (float*)p;

        const int n4 = BATCH * SEQ * DMODEL / 4;   // 2,097,152
        hipLaunchKernelGGL(convert_bf16, dim3((n4 + 255) / 256), dim3(256), 0, stream,
                           x, x_bf, n4);
        hipLaunchKernelGGL(transpose_w, dim3(32, 32, 3), dim3(32, 8), 0, stream,
                           Wq, Wk, Wv, wtq, wtk, wtv);
        hipLaunchKernelGGL(qkv_gemm_mfma, dim3(DMODEL / 128, BATCH * SEQ / 128, 3), dim3(256), 0, stream,
                           x_bf, wtq, wtk, wtv, bq, bk, bv, q_bf, k_bf, v_bf);
        hipLaunchKernelGGL(transpose_v, dim3(SEQ / 32, DMODEL / 32, BATCH), dim3(32, 8), 0, stream,
                           v_bf, vt);
        hipLaunchKernelGGL(qkt_gemm_mfma, dim3(SEQ / 128, SEQ / 128, BATCH), dim3(256), 0, stream,
                           q_bf, k_bf, sc);
        hipLaunchKernelGGL(softmax_rows, dim3(SEQ, BATCH), dim3(256), 0, stream, sc);
        hipLaunchKernelGGL(pv_gemm_mfma, dim3(DMODEL / 128, SEQ / 128, BATCH), dim3(256), 0, stream,
                           sc, vt, out);
    } else {
        // fp32 fallback (96 MB)
        const size_t elems = (size_t)BATCH * SEQ * DMODEL;
        float* q = (float*)d_ws;
        float* k = q + elems;
        float* v = k + elems;
        hipLaunchKernelGGL(qkv_gemm_f32, dim3(DMODEL / 32, BATCH * SEQ / 32, 3), dim3(32, 32), 0, stream,
                           x, Wq, bq, Wk, bk, Wv, bv, q, k, v);
        hipLaunchKernelGGL(attn_f32, dim3(SEQ, BATCH), dim3(256), 0, stream, q, k, v, out);
    }
}